// Round 2
// baseline (297.690 us; speedup 1.0000x reference)
//
#include <hip/hip_runtime.h>

#define Bn 4
#define Nn 4096000
#define Kn 409664
#define R0c 3686399u   // rank of v_lo (0-indexed); mask == key > key_lo exactly

// ws offsets (u32 units)
#define H1_OFF 0                      // Bn*2048
#define H2_OFF (Bn*2048)              // Bn*2048
#define H3_OFF (H2_OFF + Bn*2048)     // Bn*1024
#define ST_OFF (H3_OFF + Bn*1024)     // Bn*2  {prefix/key, rem}
#define CNT_OFF (ST_OFF + Bn*2)       // Bn
#define BC_OFF (CNT_OFF + Bn)         // Bn*1000

#define OUT_SP  ((size_t)Bn * Kn * 5)
#define OUT_VAL ((size_t)Bn * Kn * 9)

__device__ __forceinline__ unsigned fkey(float x) {
    unsigned u = __float_as_uint(x);
    return u ^ ((unsigned)((int)u >> 31) | 0x80000000u);
}

// ---------------- pass 1: top 11 bits, 4 per-wave histogram copies ----------------
__global__ void hist1_k(const float* __restrict__ cube, unsigned* __restrict__ ws) {
    __shared__ unsigned h[4][2048];
    int tid = threadIdx.x, blk = blockIdx.x;
    int b = blk / 250, c = blk % 250;
    int wid = tid >> 6;
    for (int j = tid; j < 8192; j += 256) ((unsigned*)h)[j] = 0;
    __syncthreads();
    const float4* p = (const float4*)(cube + (size_t)b * Nn + (size_t)c * 16384);
    for (int it = 0; it < 16; ++it) {
        float4 v = p[it * 256 + tid];
        atomicAdd(&h[wid][fkey(v.x) >> 21], 1u);
        atomicAdd(&h[wid][fkey(v.y) >> 21], 1u);
        atomicAdd(&h[wid][fkey(v.z) >> 21], 1u);
        atomicAdd(&h[wid][fkey(v.w) >> 21], 1u);
    }
    __syncthreads();
    unsigned* g = ws + H1_OFF + b * 2048;
    for (int j = tid; j < 2048; j += 256) {
        unsigned s = h[0][j] + h[1][j] + h[2][j] + h[3][j];
        if (s) atomicAdd(&g[j], s);
    }
}

__global__ void pick1_k(unsigned* __restrict__ ws) {
    __shared__ unsigned sh[256];
    int tid = threadIdx.x, b = blockIdx.x;
    const unsigned* hist = ws + H1_OFF + b * 2048;
    unsigned loc[8], lsum = 0;
    for (int j = 0; j < 8; ++j) { loc[j] = hist[tid * 8 + j]; lsum += loc[j]; }
    sh[tid] = lsum; __syncthreads();
    for (int off = 1; off < 256; off <<= 1) {
        unsigned v = (tid >= off) ? sh[tid - off] : 0u; __syncthreads();
        sh[tid] += v; __syncthreads();
    }
    unsigned base = tid ? sh[tid - 1] : 0u;
    if (R0c >= base && R0c < base + lsum) {
        unsigned cacc = base;
        for (int j = 0; j < 8; ++j) {
            if (R0c < cacc + loc[j]) {
                ws[ST_OFF + b * 2] = (unsigned)(tid * 8 + j);
                ws[ST_OFF + b * 2 + 1] = R0c - cacc;
                break;
            }
            cacc += loc[j];
        }
    }
}

// ---------------- pass 2: middle 11 bits of elements matching 11-bit prefix ----------------
__global__ void hist2_k(const float* __restrict__ cube, unsigned* __restrict__ ws) {
    __shared__ unsigned h[2048];
    int tid = threadIdx.x, blk = blockIdx.x;
    int b = blk / 250, c = blk % 250;
    unsigned p0 = ws[ST_OFF + b * 2];
    for (int j = tid; j < 2048; j += 256) h[j] = 0;
    __syncthreads();
    const float4* p = (const float4*)(cube + (size_t)b * Nn + (size_t)c * 16384);
    for (int it = 0; it < 16; ++it) {
        float4 v = p[it * 256 + tid];
        float vv[4] = {v.x, v.y, v.z, v.w};
        for (int q = 0; q < 4; ++q) {
            unsigned k = fkey(vv[q]);
            if ((k >> 21) == p0) atomicAdd(&h[(k >> 10) & 0x7FFu], 1u);
        }
    }
    __syncthreads();
    unsigned* g = ws + H2_OFF + b * 2048;
    for (int j = tid; j < 2048; j += 256) if (h[j]) atomicAdd(&g[j], h[j]);
}

__global__ void pick2_k(unsigned* __restrict__ ws) {
    __shared__ unsigned sh[256];
    int tid = threadIdx.x, b = blockIdx.x;
    const unsigned* hist = ws + H2_OFF + b * 2048;
    unsigned r = ws[ST_OFF + b * 2 + 1];
    unsigned pref = ws[ST_OFF + b * 2];
    unsigned loc[8], lsum = 0;
    for (int j = 0; j < 8; ++j) { loc[j] = hist[tid * 8 + j]; lsum += loc[j]; }
    sh[tid] = lsum; __syncthreads();
    for (int off = 1; off < 256; off <<= 1) {
        unsigned v = (tid >= off) ? sh[tid - off] : 0u; __syncthreads();
        sh[tid] += v; __syncthreads();
    }
    unsigned base = tid ? sh[tid - 1] : 0u;
    if (r >= base && r < base + lsum) {
        unsigned cacc = base;
        for (int j = 0; j < 8; ++j) {
            if (r < cacc + loc[j]) {
                ws[ST_OFF + b * 2] = (pref << 11) | (unsigned)(tid * 8 + j);
                ws[ST_OFF + b * 2 + 1] = r - cacc;
                break;
            }
            cacc += loc[j];
        }
    }
}

// ---------------- pass 3: low 10 bits of elements matching 22-bit prefix ----------------
__global__ void hist3_k(const float* __restrict__ cube, unsigned* __restrict__ ws) {
    __shared__ unsigned h[1024];
    int tid = threadIdx.x, blk = blockIdx.x;
    int b = blk / 250, c = blk % 250;
    unsigned p0 = ws[ST_OFF + b * 2];
    for (int j = tid; j < 1024; j += 256) h[j] = 0;
    __syncthreads();
    const float4* p = (const float4*)(cube + (size_t)b * Nn + (size_t)c * 16384);
    for (int it = 0; it < 16; ++it) {
        float4 v = p[it * 256 + tid];
        float vv[4] = {v.x, v.y, v.z, v.w};
        for (int q = 0; q < 4; ++q) {
            unsigned k = fkey(vv[q]);
            if ((k >> 10) == p0) atomicAdd(&h[k & 0x3FFu], 1u);
        }
    }
    __syncthreads();
    unsigned* g = ws + H3_OFF + b * 1024;
    for (int j = tid; j < 1024; j += 256) if (h[j]) atomicAdd(&g[j], h[j]);
}

__global__ void pick3_k(unsigned* __restrict__ ws) {
    __shared__ unsigned sh[256];
    int tid = threadIdx.x, b = blockIdx.x;
    const unsigned* hist = ws + H3_OFF + b * 1024;
    unsigned r = ws[ST_OFF + b * 2 + 1];
    unsigned pref = ws[ST_OFF + b * 2];
    unsigned loc[4], lsum = 0;
    for (int j = 0; j < 4; ++j) { loc[j] = hist[tid * 4 + j]; lsum += loc[j]; }
    sh[tid] = lsum; __syncthreads();
    for (int off = 1; off < 256; off <<= 1) {
        unsigned v = (tid >= off) ? sh[tid - off] : 0u; __syncthreads();
        sh[tid] += v; __syncthreads();
    }
    unsigned base = tid ? sh[tid - 1] : 0u;
    if (r >= base && r < base + lsum) {
        unsigned cacc = base;
        for (int j = 0; j < 4; ++j) {
            if (r < cacc + loc[j]) {
                // final 32-bit key of v_lo; mask = key > key_lo
                ws[ST_OFF + b * 2] = (pref << 10) | (unsigned)(tid * 4 + j);
                break;
            }
            cacc += loc[j];
        }
    }
}

// ---------------- per-block mask counts (u32 key compare) ----------------
__global__ void count_k(const float* __restrict__ cube, unsigned* __restrict__ ws) {
    __shared__ unsigned sh[4];
    int tid = threadIdx.x, blk = blockIdx.x;
    int b = blk / 1000, c = blk % 1000;
    unsigned key_lo = ws[ST_OFF + b * 2];
    const float4* p = (const float4*)(cube + (size_t)b * Nn + (size_t)c * 4096);
    unsigned cnt = 0;
    for (int it = 0; it < 4; ++it) {
        float4 v = p[it * 256 + tid];
        cnt += (fkey(v.x) > key_lo) + (fkey(v.y) > key_lo)
             + (fkey(v.z) > key_lo) + (fkey(v.w) > key_lo);
    }
    for (int off = 32; off > 0; off >>= 1) cnt += __shfl_down(cnt, off, 64);
    if ((tid & 63) == 0) sh[tid >> 6] = cnt;
    __syncthreads();
    if (tid == 0) ws[BC_OFF + b * 1000 + c] = sh[0] + sh[1] + sh[2] + sh[3];
}

// ---------------- exclusive scan of 1000 block counts per sample ----------------
__global__ void scan_k(unsigned* __restrict__ ws) {
    __shared__ unsigned sh[256];
    int tid = threadIdx.x, b = blockIdx.x;
    unsigned* bc = ws + BC_OFF + b * 1000;
    unsigned loc[4], lsum = 0;
    for (int j = 0; j < 4; ++j) {
        int idx = tid * 4 + j;
        loc[j] = (idx < 1000) ? bc[idx] : 0u;
        lsum += loc[j];
    }
    sh[tid] = lsum; __syncthreads();
    for (int off = 1; off < 256; off <<= 1) {
        unsigned v = (tid >= off) ? sh[tid - off] : 0u; __syncthreads();
        sh[tid] += v; __syncthreads();
    }
    unsigned run = tid ? sh[tid - 1] : 0u;
    for (int j = 0; j < 4; ++j) {
        int idx = tid * 4 + j;
        if (idx < 1000) bc[idx] = run;
        run += loc[j];
    }
    if (tid == 255) ws[CNT_OFF + b] = sh[255];
}

// ---------------- ordered scatter: thread owns 16 contiguous elements ----------------
__global__ void scatter_k(const float* __restrict__ cube, const float* __restrict__ dop,
                          float* __restrict__ out, const unsigned* __restrict__ ws) {
    __shared__ unsigned sh[256];
    int tid = threadIdx.x, blk = blockIdx.x;
    int b = blk / 1000, c = blk % 1000;
    unsigned key_lo = ws[ST_OFF + b * 2];
    unsigned run0 = ws[BC_OFF + b * 1000 + c];
    const float* cb = cube + (size_t)b * Nn;
    const float* db = dop + (size_t)b * Nn;
    int i0 = c * 4096 + tid * 16;

    const float4* p = (const float4*)(cb + i0);
    float4 v0 = p[0], v1 = p[1], v2 = p[2], v3 = p[3];
    float v[16] = {v0.x, v0.y, v0.z, v0.w, v1.x, v1.y, v1.z, v1.w,
                   v2.x, v2.y, v2.z, v2.w, v3.x, v3.y, v3.z, v3.w};
    unsigned m = 0, cnt = 0;
#pragma unroll
    for (int j = 0; j < 16; ++j) {
        if (fkey(v[j]) > key_lo) { m |= (1u << j); ++cnt; }
    }
    sh[tid] = cnt; __syncthreads();
    for (int off = 1; off < 256; off <<= 1) {
        unsigned t = (tid >= off) ? sh[tid - off] : 0u; __syncthreads();
        sh[tid] += t; __syncthreads();
    }
    unsigned k = run0 + sh[tid] - cnt;

    // 16-element chunk never crosses an x-row (320 = 20*16): x/y/z computed once
    int xi0 = i0 % 320;
    int t2 = i0 / 320;
    int yi = t2 % 320;
    int zi = t2 / 320;
    float yc = (float)yi / 320.0f * 32.0f;
    float zc = (float)zi / 40.0f * 8.0f;
    float fb = (float)b, fzi = (float)zi, fyi = (float)yi;

#pragma unroll
    for (int j = 0; j < 16; ++j) {
        if (m & (1u << j)) {
            int xi = xi0 + j;
            size_t row = (size_t)b * Kn + k;
            float* f = out + row * 5;
            f[0] = (float)xi / 320.0f * 72.0f;
            f[1] = yc; f[2] = zc;
            f[3] = v[j] / 1e13f;
            f[4] = db[i0 + j] - 1.9326f;
            float* s = out + OUT_SP + row * 4;
            s[0] = fb; s[1] = fzi; s[2] = fyi; s[3] = (float)xi;
            out[OUT_VAL + row] = 1.0f;
            ++k;
        }
    }
}

// ---------------- zero-fill invalid tail rows ----------------
__global__ void fill_k(float* __restrict__ out, const unsigned* __restrict__ ws) {
    int g = blockIdx.x * 256 + threadIdx.x;
    if (g >= Bn * Kn) return;
    int b = g / Kn;
    int k = g - b * Kn;
    if ((unsigned)k >= ws[CNT_OFF + b]) {
        size_t row = (size_t)g;
        float* f = out + row * 5;
        f[0] = 0.f; f[1] = 0.f; f[2] = 0.f; f[3] = 0.f; f[4] = 0.f;
        float* s = out + OUT_SP + row * 4;
        s[0] = 0.f; s[1] = 0.f; s[2] = 0.f; s[3] = 0.f;
        out[OUT_VAL + row] = 0.f;
    }
}

extern "C" void kernel_launch(void* const* d_in, const int* in_sizes, int n_in,
                              void* d_out, int out_size, void* d_ws, size_t ws_size,
                              hipStream_t stream) {
    const float* cube = (const float*)d_in[0];
    const float* dop = (const float*)d_in[1];
    float* out = (float*)d_out;
    unsigned* ws = (unsigned*)d_ws;

    // zero only the histogram regions; ST/CNT/BC are fully overwritten each call
    hipMemsetAsync(d_ws, 0, (size_t)ST_OFF * sizeof(unsigned), stream);

    hipLaunchKernelGGL(hist1_k, dim3(Bn * 250), dim3(256), 0, stream, cube, ws);
    hipLaunchKernelGGL(pick1_k, dim3(Bn), dim3(256), 0, stream, ws);
    hipLaunchKernelGGL(hist2_k, dim3(Bn * 250), dim3(256), 0, stream, cube, ws);
    hipLaunchKernelGGL(pick2_k, dim3(Bn), dim3(256), 0, stream, ws);
    hipLaunchKernelGGL(hist3_k, dim3(Bn * 250), dim3(256), 0, stream, cube, ws);
    hipLaunchKernelGGL(pick3_k, dim3(Bn), dim3(256), 0, stream, ws);
    hipLaunchKernelGGL(count_k, dim3(Bn * 1000), dim3(256), 0, stream, cube, ws);
    hipLaunchKernelGGL(scan_k, dim3(Bn), dim3(256), 0, stream, ws);
    hipLaunchKernelGGL(scatter_k, dim3(Bn * 1000), dim3(256), 0, stream, cube, dop, out, ws);
    hipLaunchKernelGGL(fill_k, dim3((Bn * Kn + 255) / 256), dim3(256), 0, stream, out, ws);
}